// Round 14
// baseline (1200.233 us; speedup 1.0000x reference)
//
#include <hip/hip_runtime.h>
#include <hip/hip_bf16.h>
#include <math.h>

#define B_ 512
#define E_ 256
#define H_ 512
#define V_ 4096
#define T_ 18
#define L_ 20
#define MARGIN_ 0.04f
#define CCAP_ 64

typedef __attribute__((ext_vector_type(8))) short bf16x8;
typedef __attribute__((ext_vector_type(4))) float f32x4;

// ========== prep: cat fp32 + WoutB bf16 + curTok=SOS (one kernel) ==========
__global__ __launch_bounds__(256) void kprep32(const float* __restrict__ pa,
                                               const float* __restrict__ pb,
                                               const float* __restrict__ Wout,
                                               float* __restrict__ cat,
                                               __hip_bfloat16* __restrict__ WB,
                                               int* __restrict__ curTok) {
  int idx = blockIdx.x * 256 + threadIdx.x;
  if (idx < 524288) {
    int b = idx >> 10, k = idx & 1023;
    cat[idx] = (k < 512) ? pa[b * 512 + k] : pb[b * 512 + (k - 512)];
  } else if (idx < 524288 + 2097152) {
    int i = idx - 524288;
    WB[i] = __float2bfloat16(Wout[i]);
  } else {
    int b = idx - 2621440;
    if (b < B_) curTok[b] = 1;   // SOS
  }
}

// ===== fp32 GEMM, 128x128 tile, 8x8/thread, split-K — vectorized =====
// P[z][M,N] = A[M,K_z] @ W[N,K_z]^T. grid (N/128, M/128, S); kPer = K/S (x16).
// float4 staging, consecutive-8 fragments (ds_read_b128), float4 stores.
__global__ __launch_bounds__(256) void sgemm128(const float* __restrict__ A,
                                                const float* __restrict__ W,
                                                float* __restrict__ P,
                                                int N, int lda, int kPer) {
  __shared__ float As[16][132];
  __shared__ float Bs[16][132];
  const int tid = threadIdx.x;
  const int tx = tid & 15, ty = tid >> 4;
  const int bn = blockIdx.x * 128, bm = blockIdx.y * 128;
  const int k0 = blockIdx.z * kPer;
  const size_t pOff = (size_t)blockIdx.z * (size_t)gridDim.y * 128 * N;
  const int r1 = tid >> 2;              // staging row (0..63), +64 for 2nd
  const int kq = (tid & 3) * 4;         // staging k quad

  float acc[8][8] = {};
  for (int kb = 0; kb < kPer; kb += 16) {
    const float* Ap = A + (size_t)(bm + r1) * lda + k0 + kb + kq;
    const float* Wp = W + (size_t)(bn + r1) * lda + k0 + kb + kq;
    float4 a1 = *reinterpret_cast<const float4*>(Ap);
    float4 a2 = *reinterpret_cast<const float4*>(Ap + (size_t)64 * lda);
    float4 b1 = *reinterpret_cast<const float4*>(Wp);
    float4 b2 = *reinterpret_cast<const float4*>(Wp + (size_t)64 * lda);
    As[kq + 0][r1] = a1.x; As[kq + 1][r1] = a1.y;
    As[kq + 2][r1] = a1.z; As[kq + 3][r1] = a1.w;
    As[kq + 0][r1 + 64] = a2.x; As[kq + 1][r1 + 64] = a2.y;
    As[kq + 2][r1 + 64] = a2.z; As[kq + 3][r1 + 64] = a2.w;
    Bs[kq + 0][r1] = b1.x; Bs[kq + 1][r1] = b1.y;
    Bs[kq + 2][r1] = b1.z; Bs[kq + 3][r1] = b1.w;
    Bs[kq + 0][r1 + 64] = b2.x; Bs[kq + 1][r1 + 64] = b2.y;
    Bs[kq + 2][r1 + 64] = b2.z; Bs[kq + 3][r1 + 64] = b2.w;
    __syncthreads();
#pragma unroll
    for (int kk = 0; kk < 16; ++kk) {
      float a[8], b[8];
#pragma unroll
      for (int i = 0; i < 8; ++i) a[i] = As[kk][ty * 8 + i];
#pragma unroll
      for (int j = 0; j < 8; ++j) b[j] = Bs[kk][tx * 8 + j];
#pragma unroll
      for (int i = 0; i < 8; ++i)
#pragma unroll
        for (int j = 0; j < 8; ++j) acc[i][j] = fmaf(a[i], b[j], acc[i][j]);
    }
    __syncthreads();
  }
#pragma unroll
  for (int i = 0; i < 8; ++i) {
    size_t r = (size_t)(bm + ty * 8 + i);
    float4 v0 = make_float4(acc[i][0], acc[i][1], acc[i][2], acc[i][3]);
    float4 v1 = make_float4(acc[i][4], acc[i][5], acc[i][6], acc[i][7]);
    float4* dst = reinterpret_cast<float4*>(P + pOff + r * N + bn + tx * 8);
    dst[0] = v0;
    dst[1] = v1;
  }
}

// ======== h0 = sum of 8 partials + b_init (fp64 sum); fp32 + bf16 out ======
__global__ __launch_bounds__(256) void reduceH0(const float* __restrict__ parts,
                                                const float* __restrict__ binit,
                                                float* __restrict__ h,
                                                __hip_bfloat16* __restrict__ hB) {
  int i = blockIdx.x * 256 + threadIdx.x;   // < 262144
  double s = (double)binit[i & 511];
#pragma unroll
  for (int c = 0; c < 8; ++c) s += (double)parts[(size_t)c * 262144 + i];
  float f = (float)s;
  h[i] = f;
  hB[i] = __float2bfloat16(f);
}

// ====== gates: sum 8 gh partials + gather gi + GRU update (fp32 gates) ======
__global__ __launch_bounds__(256) void gates32(const float* __restrict__ ghP,
                                               const float* __restrict__ giP,
                                               const float* __restrict__ bih,
                                               const float* __restrict__ bhh,
                                               const int* __restrict__ curTok,
                                               float* __restrict__ h,
                                               __hip_bfloat16* __restrict__ hB) {
  int idx = blockIdx.x * 256 + threadIdx.x;   // < B_*H_
  int b = idx >> 9, j = idx & (H_ - 1);
  size_t base = (size_t)b * 1536;
  double gr = (double)bhh[j], gz = (double)bhh[512 + j], gn = (double)bhh[1024 + j];
#pragma unroll
  for (int s = 0; s < 8; ++s) {
    const float* p = ghP + (size_t)s * 786432 + base;
    gr += (double)p[j]; gz += (double)p[512 + j]; gn += (double)p[1024 + j];
  }
  const float* g0 = giP + (size_t)curTok[b] * 1536;
  float ir  = g0[j]        + bih[j];
  float iz  = g0[512 + j]  + bih[512 + j];
  float inn = g0[1024 + j] + bih[1024 + j];
  float r = 1.f / (1.f + expf(-(ir + (float)gr)));
  float z = 1.f / (1.f + expf(-(iz + (float)gz)));
  float n = tanhf(inn + r * (float)gn);
  float hn = (1.f - z) * n + z * h[idx];
  h[idx] = hn;
  hB[idx] = __float2bfloat16(hn);
}

// ====== bf16 MFMA screen: loP[512,4096] = hB[512,512] @ WB[4096,512]^T ======
__global__ __launch_bounds__(256) void mfma_screen(const __hip_bfloat16* __restrict__ hB,
                                                   const __hip_bfloat16* __restrict__ WB,
                                                   float* __restrict__ P) {
  const int wave = threadIdx.x >> 6, lane = threadIdx.x & 63;
  const int bm = blockIdx.y * 64 + wave * 16;
  const int bn = blockIdx.x * 64;
  const int rA = lane & 15, g = lane >> 4;
  const __hip_bfloat16* ha = hB + (size_t)(bm + rA) * H_ + g * 8;
  const __hip_bfloat16* wb = WB + (size_t)(bn + rA) * H_ + g * 8;
  f32x4 acc[4] = {};
  for (int k0 = 0; k0 < H_; k0 += 32) {
    bf16x8 a = *reinterpret_cast<const bf16x8*>(ha + k0);
#pragma unroll
    for (int j = 0; j < 4; ++j) {
      bf16x8 b = *reinterpret_cast<const bf16x8*>(wb + (size_t)j * 16 * H_ + k0);
      acc[j] = __builtin_amdgcn_mfma_f32_16x16x32_bf16(a, b, acc[j], 0, 0, 0);
    }
  }
#pragma unroll
  for (int j = 0; j < 4; ++j)
#pragma unroll
    for (int r = 0; r < 4; ++r)
      P[(size_t)(bm + g * 4 + r) * V_ + bn + j * 16 + rA] = acc[j][r];
}

// ====== pickTok: fp32 screen + candidate-only fp64 rescore ======
__global__ __launch_bounds__(256) void pickTok(const float* __restrict__ loP,
                                               const float* __restrict__ h,
                                               const float* __restrict__ Wout,
                                               const float* __restrict__ bout,
                                               const float* __restrict__ u,  // step slice
                                               int* __restrict__ toks,
                                               int* __restrict__ curTok,
                                               int t) {
  int b = blockIdx.x, tid = threadIdx.x;
  const float* l0 = loP + (size_t)b * V_;
  const float* ub = u + (size_t)b * V_;
  float sloc[16];
  float best = -1e30f; int bi = 0x7fffffff;
#pragma unroll
  for (int i = 0; i < 16; ++i) {
    int v = tid + 256 * i;
    float s = l0[v] + bout[v] - logf(-logf(ub[v]));   // fp32 screen score
    sloc[i] = s;
    if (s > best) { best = s; bi = v; }   // per-thread v ascending: > = first occ.
  }
  __shared__ float  sv[256];
  __shared__ int    si[256];
  __shared__ int    pre[256];
  __shared__ int    candV[CCAP_];
  __shared__ double sd[256];
  __shared__ double bestS;
  __shared__ int    bestV;
  sv[tid] = best; si[tid] = bi;
  __syncthreads();
  for (int st = 128; st > 0; st >>= 1) {
    if (tid < st) {
      float ov = sv[tid + st]; int oi = si[tid + st];
      if (ov > sv[tid] || (ov == sv[tid] && oi < si[tid])) { sv[tid] = ov; si[tid] = oi; }
    }
    __syncthreads();
  }
  float smax = sv[0];
  int amax = si[0];
  __syncthreads();
  int c = 0; int lv[16];
#pragma unroll
  for (int i = 0; i < 16; ++i)
    if (sloc[i] >= smax - MARGIN_) { if (c < 16) lv[c] = tid + 256 * i; ++c; }
  pre[tid] = c;
  __syncthreads();
  for (int off = 1; off < 256; off <<= 1) {          // inclusive prefix scan
    int vv = (tid >= off) ? pre[tid - off] : 0;
    __syncthreads();
    pre[tid] += vv;
    __syncthreads();
  }
  int tot = pre[255];
  int base = pre[tid] - c;
  if (tot <= CCAP_)
    for (int q = 0; q < c; ++q) candV[base + q] = lv[q];
  __syncthreads();
  int tok;
  if (tot == 1) {
    tok = amax;                                       // screen error << margin
  } else if (tot <= CCAP_) {
    const float* hb = h + (size_t)b * H_;
    if (tid == 0) { bestS = -1e300; bestV = 0x7fffffff; }
    __syncthreads();
    for (int ci = 0; ci < tot; ++ci) {
      int v = candV[ci];
      const float* wr = Wout + (size_t)v * H_;
      double p = (double)hb[tid] * (double)wr[tid]
               + (double)hb[tid + 256] * (double)wr[tid + 256];
      sd[tid] = p;
      __syncthreads();
      for (int st = 128; st > 0; st >>= 1) {
        if (tid < st) sd[tid] += sd[tid + st];
        __syncthreads();
      }
      if (tid == 0) {
        double s = sd[0] + (double)bout[v] - log(-log((double)ub[v]));
        if (s > bestS || (s == bestS && v < bestV)) { bestS = s; bestV = v; }
      }
      __syncthreads();
    }
    tok = bestV;
  } else {
    // safety net: full-row fp64 rescore (statistically unreachable)
    const float* hb = h + (size_t)b * H_;
    double dbest = -1e300; bi = 0x7fffffff;
    for (int i = 0; i < 16; ++i) {
      int v = tid + 256 * i;
      const float* wr = Wout + (size_t)v * H_;
      double dot = 0.0;
      for (int k = 0; k < H_; ++k) dot = fma((double)hb[k], (double)wr[k], dot);
      double s = dot + (double)bout[v] - log(-log((double)ub[v]));
      if (s > dbest) { dbest = s; bi = v; }
    }
    sd[tid] = dbest; si[tid] = bi;
    __syncthreads();
    for (int st = 128; st > 0; st >>= 1) {
      if (tid < st) {
        double ov = sd[tid + st]; int oi = si[tid + st];
        if (ov > sd[tid] || (ov == sd[tid] && oi < si[tid])) { sd[tid] = ov; si[tid] = oi; }
      }
      __syncthreads();
    }
    tok = si[0];
  }
  if (tid == 0) { toks[t * B_ + b] = tok; curTok[b] = tok; }
}

// ============== final: zero + one-hot scatter + SOS/EOS, fp32 ==============
__global__ __launch_bounds__(256) void kfinal32(float* __restrict__ out,
                                                const int* __restrict__ toks) {
  size_t c = (size_t)blockIdx.x * 256 + threadIdx.x;   // one float4
  size_t e0 = c * 4;
  int v0 = (int)(e0 & (size_t)(V_ - 1));
  size_t row = e0 >> 12;                               // b*L + p
  int p = (int)(row % L_);
  int b = (int)(row / L_);
  int tok;
  if (p == 0)           tok = 1;                       // SOS
  else if (p == L_ - 1) tok = 2;                       // EOS
  else                  tok = toks[(p - 1) * B_ + b];
  float4 val = make_float4(0.f, 0.f, 0.f, 0.f);
  int d = tok - v0;
  if (d >= 0 && d < 4) {
    if (d == 0) val.x = 1.f; else if (d == 1) val.y = 1.f;
    else if (d == 2) val.z = 1.f; else val.w = 1.f;
  }
  reinterpret_cast<float4*>(out)[c] = val;
}

// ---------------- environment markers ----------------
__global__ void kmark_ws(float* out) {
  if (threadIdx.x == 0) out[0] = 16.0f;
}
__global__ void kmark_resolver(float* out) {
  if (threadIdx.x == 0) out[2] = 11.0f;
}

// ================================ launch ================================
extern "C" void kernel_launch(void* const* d_in, const int* in_sizes, int n_in,
                              void* d_out, int out_size, void* d_ws, size_t ws_size,
                              hipStream_t stream) {
  static const int EXPECT[12] = {262144, 262144, 524288, 512, 393216, 786432,
                                 1536, 1536, 2097152, 4096, 1048576, 37748736};
  const float* R[12];
  bool resolved = (n_in == 12);
  if (resolved) {
    bool used[12] = {};
    for (int i = 0; i < 12; ++i) {
      int f = -1;
      for (int j = 0; j < 12; ++j)
        if (!used[j] && in_sizes[j] == EXPECT[i]) { f = j; break; }
      if (f < 0) { resolved = false; break; }
      used[f] = true;
      R[i] = (const float*)d_in[f];
    }
  }
  if (!resolved)
    for (int i = 0; i < 12 && i < n_in; ++i) R[i] = (const float*)d_in[i];

  const float *pa = R[0], *pb = R[1], *Winit = R[2], *binit = R[3],
              *Wih = R[4], *Whh = R[5], *bih = R[6], *bhh = R[7],
              *Wout = R[8], *bout = R[9], *emb = R[10], *ug = R[11];
  float* out = (float*)d_out;

  const size_t TOK_BYTES = (size_t)T_ * B_ * sizeof(int);   // 36864
  if (ws_size < TOK_BYTES) { kmark_ws<<<1, 64, 0, stream>>>(out); return; }
  int* toks = (int*)d_ws;

  // curTok in d_out tail (rebuilt by kfinal32 at the very end)
  size_t out_bytes = (size_t)out_size * 4;
  int* curTok = (int*)((char*)d_out + out_bytes - 2048);

  // scratch (fp32-equivalent units, 16,121,856 floats = 64.5 MB):
  //  h | giP(1 chunk) | ghP(8 chunks, aliases cat+h0P pre-loop) | loP | hB | WoutB
  const size_t SC_FLOATS = 16121856;
  float* sc;
  if (ws_size >= 40960 + SC_FLOATS * sizeof(float)) {
    sc = (float*)((char*)d_ws + 40960);
  } else {
    sc = (float*)d_out;   // head of 167.8 MB out; kfinal32 rebuilds last
  }
  float* h    = sc;                                   // 262,144
  float* giP  = sc + 262144;                          // 6,291,456 (4096x1536)
  float* ghP  = sc + 6553600;                         // 6,291,456 (8 x 512x1536)
  float* loP  = sc + 12845056;                        // 2,097,152 (512x4096)
  __hip_bfloat16* hB    = (__hip_bfloat16*)(sc + 14942208);   // 262,144 bf16
  __hip_bfloat16* WoutB = (__hip_bfloat16*)(sc + 15073280);   // 2,097,152 bf16
  float* cat  = ghP;                                  // 524,288   (pre-loop only)
  float* h0P  = ghP + 524288;                         // 8 x 262,144 (pre-loop only)

  // ---- setup ----
  kprep32<<<10242, 256, 0, stream>>>(pa, pb, Wout, cat, WoutB, curTok);
  // h0 partials: cat[512,1024] @ Winit[512,1024]^T, split-K=8
  sgemm128<<<dim3(4, 4, 8), 256, 0, stream>>>(cat, Winit, h0P, 512, 1024, 128);
  reduceH0<<<1024, 256, 0, stream>>>(h0P, binit, h, hB);
  // giP = emb[4096,256] @ Wih[1536,256]^T, single chunk
  sgemm128<<<dim3(12, 32, 1), 256, 0, stream>>>(emb, Wih, giP, 1536, 256, 256);

  // ---- decode loop ----
  for (int t = 0; t < T_; ++t) {
    // ghP = h[512,512] @ Whh[1536,512]^T, split-K=8
    sgemm128<<<dim3(12, 4, 8), 256, 0, stream>>>(h, Whh, ghP, 1536, 512, 64);
    gates32<<<1024, 256, 0, stream>>>(ghP, giP, bih, bhh, curTok, h, hB);
    // loP = hB @ WoutB^T via bf16 MFMA (margin-protected screen)
    mfma_screen<<<dim3(64, 8), 256, 0, stream>>>(hB, WoutB, loP);
    pickTok<<<512, 256, 0, stream>>>(loP, h, Wout, bout,
                                     ug + (size_t)t * B_ * V_, toks, curTok, t);
  }

  // ---- assemble fp32 output ----
  kfinal32<<<40960, 256, 0, stream>>>(out, toks);
  if (!resolved) kmark_resolver<<<1, 64, 0, stream>>>(out);
}